// Round 3
// baseline (3886.311 us; speedup 1.0000x reference)
//
#include <hip/hip_runtime.h>
#include <math.h>

// Problem constants (fixed by the reference setup)
constexpr int B_  = 16;
constexpr int CH  = 512;
constexpr int HW  = 128 * 128;   // 16384
constexpr int C_  = 16;          // selected classes
constexpr int G_  = 32;          // channel groups = CH / C_
constexpr int NP  = (C_ * (C_ - 1)) / 2;  // 120 off-diagonal upper pairs
constexpr int NSPLIT = 8;        // HW-axis split per (b,g)
constexpr int HWS = HW / NSPLIT; // 2048 points per split
constexpr int T_  = 512;         // points per LDS tile
constexpr int NT  = HWS / T_;    // 4 tiles per block
constexpr int PPW = NP / 4;      // 30 pairs per wave

// ---------------------------------------------------------------------------
// Kernel 0: per selected class, top-G channels of |w| in descending order
// (stable tie-break by smaller index, matching jnp.argsort(-w_abs)), plus
// sigmoid(|w|) weights. One wave per class; 512 values in registers.
// perm_tbl[k*C + j] = idx[sel[j]][k],  wgh_tbl[k*C + j] = sigmoid(|w|)
// ---------------------------------------------------------------------------
__global__ __launch_bounds__(64)
void topk_kernel(const float* __restrict__ w, const int* __restrict__ sel,
                 int* __restrict__ perm_tbl, float* __restrict__ wgh_tbl) {
  const int j    = blockIdx.x;
  const int lane = threadIdx.x;
  const float* wr = w + (size_t)sel[j] * CH;

  float vals[8];
#pragma unroll
  for (int i = 0; i < 8; ++i) vals[i] = fabsf(wr[lane * 8 + i]);

  for (int k = 0; k < G_; ++k) {
    float bv = vals[0];
    int bloc = 0;
#pragma unroll
    for (int i = 1; i < 8; ++i)
      if (vals[i] > bv) { bv = vals[i]; bloc = i; }
    int bi = lane * 8 + bloc;

#pragma unroll
    for (int m = 1; m < 64; m <<= 1) {
      float ov = __shfl_xor(bv, m);
      int   oi = __shfl_xor(bi, m);
      if (ov > bv || (ov == bv && oi < bi)) { bv = ov; bi = oi; }
    }

    if (lane == 0) {
      perm_tbl[k * C_ + j] = bi;
      wgh_tbl [k * C_ + j] = 1.0f / (1.0f + expf(-bv));
    }

    if ((bi >> 3) == lane) {
#pragma unroll
      for (int i = 0; i < 8; ++i)
        if ((bi & 7) == i) vals[i] = -1.0f;
    }
  }
}

// ---------------------------------------------------------------------------
// Pair index decode (folds to constants under full unroll)
// ---------------------------------------------------------------------------
__device__ inline constexpr int pair_c(int p) {
  int c = 0, rem = p;
  while (rem >= C_ - 1 - c) { rem -= C_ - 1 - c; ++c; }
  return c;
}
__device__ inline constexpr int pair_d(int p) {
  int c = 0, rem = p;
  while (rem >= C_ - 1 - c) { rem -= C_ - 1 - c; ++c; }
  return c + 1 + rem;
}

// Per-wave pair compute: wave W owns pairs [W*30, W*30+30).
// tile points at [16][T_] floats in LDS. Lane reads float2 per channel
// (8-B lane stride = 2-way bank aliasing = free).
template <int W>
__device__ inline void compute_pairs(const float* __restrict__ tile, int lane,
                                     float* __restrict__ acc) {
#pragma unroll
  for (int j = 0; j < T_ / 128; ++j) {   // 4
    float2 v[C_];
#pragma unroll
    for (int c = 0; c < C_; ++c)
      v[c] = *(const float2*)(tile + c * T_ + j * 128 + 2 * lane);
#pragma unroll
    for (int p = W * PPW; p < W * PPW + PPW; ++p) {
      const int cc = pair_c(p);
      const int dd = pair_d(p);
      const int a  = p - W * PPW;
      acc[a] = fmaf(v[cc].x, v[dd].x, acc[a]);
      acc[a] = fmaf(v[cc].y, v[dd].y, acc[a]);
    }
  }
}

// ---------------------------------------------------------------------------
// Kernel 1: one block per (b, g, split), 256 threads = 4 waves.
// Double-buffered LDS staging via global_load_lds (width 16), pairs split
// 30-per-wave. Writes 120 per-(b,g,split) partial sums (no abs yet).
// ---------------------------------------------------------------------------
__global__ __launch_bounds__(256, 2)
void gram_part_kernel(const float* __restrict__ x,
                      const int* __restrict__ perm_tbl,
                      float* __restrict__ part) {
  const int bid   = blockIdx.x;            // b*(G*NSPLIT) + g*NSPLIT + split
  const int split = bid & (NSPLIT - 1);
  const int bg    = bid / NSPLIT;
  const int b     = bg >> 5;               // / G_
  const int g     = bg & (G_ - 1);
  const int t     = threadIdx.x;
  const int wv    = t >> 6;
  const int lane  = t & 63;

  __shared__ float s_x[2][C_][T_];         // 64 KB double buffer
  __shared__ int   s_ch[C_];
  if (t < C_) s_ch[t] = perm_tbl[g * C_ + t];
  __syncthreads();

  const float* bb = x + (size_t)b * ((size_t)CH * HW) + split * HWS;
  int off[C_];
#pragma unroll
  for (int c = 0; c < C_; ++c) off[c] = s_ch[c] * HW;

  // Stage tile k into buffer buf: 16 ch x 512 floats = 2048 float4,
  // 8 per thread. Each wave's 64 float4s are contiguous within one channel
  // in both global and LDS -> global_load_lds width=16 is valid.
  auto stage = [&](int buf, int k) {
#pragma unroll
    for (int it = 0; it < 8; ++it) {
      const int idx = it * 256 + t;
      const int ch  = idx >> 7;            // 128 float4 per channel
      const int q4  = idx & 127;
      const float* gaddr = bb + off[ch] + k * T_ + q4 * 4;
      __builtin_amdgcn_global_load_lds(
          (const __attribute__((address_space(1))) void*)gaddr,
          (__attribute__((address_space(3))) void*)&s_x[buf][ch][q4 * 4],
          16, 0, 0);
    }
  };

  float acc[PPW];
#pragma unroll
  for (int i = 0; i < PPW; ++i) acc[i] = 0.0f;

  stage(0, 0);
  for (int k = 0; k < NT; ++k) {
    __syncthreads();                       // drains vmcnt: buffer k&1 ready
    if (k + 1 < NT) stage((k + 1) & 1, k + 1);  // async prefetch overlaps compute
    const float* tile = &s_x[k & 1][0][0];
    switch (wv) {
      case 0: compute_pairs<0>(tile, lane, acc); break;
      case 1: compute_pairs<1>(tile, lane, acc); break;
      case 2: compute_pairs<2>(tile, lane, acc); break;
      default: compute_pairs<3>(tile, lane, acc); break;
    }
  }

  // 64-lane butterfly reduce each of the wave's 30 pair accumulators
#pragma unroll
  for (int i = 0; i < PPW; ++i) {
    float a = acc[i];
#pragma unroll
    for (int m = 1; m < 64; m <<= 1) a += __shfl_xor(a, m);
    acc[i] = a;
  }
  if (lane == 0) {
    float* p = part + (size_t)bid * NP + wv * PPW;
#pragma unroll
    for (int i = 0; i < PPW; ++i) p[i] = acc[i];
  }
}

// ---------------------------------------------------------------------------
// Kernel 2: one block per (b, g). Sum the NSPLIT split partials per pair,
// apply |.| * w_c * w_d, block-reduce, one atomicAdd per block.
// ---------------------------------------------------------------------------
__global__ __launch_bounds__(128)
void finalize_kernel(const float* __restrict__ part,
                     const float* __restrict__ wgh_tbl,
                     float* __restrict__ out) {
  const int bg = blockIdx.x;
  const int g  = bg & (G_ - 1);
  const int t  = threadIdx.x;

  float v = 0.0f;
  if (t < NP) {
    const float* p = part + (size_t)bg * NSPLIT * NP + t;
    float s = 0.0f;
#pragma unroll
    for (int sp = 0; sp < NSPLIT; ++sp) s += p[sp * NP];
    int cc = 0, rem = t;
    while (rem >= (C_ - 1) - cc) { rem -= (C_ - 1) - cc; ++cc; }
    int dd = cc + 1 + rem;
    v = fabsf(s) * wgh_tbl[g * C_ + cc] * wgh_tbl[g * C_ + dd];
  }

  __shared__ float s_red[128];
  s_red[t] = v;
  __syncthreads();
  for (int st = 64; st > 0; st >>= 1) {
    if (t < st) s_red[t] += s_red[t + st];
    __syncthreads();
  }

  if (t == 0) {
    // loss = sum_{b,g,c<d} w_c w_d |dot| / (NP * (HW-1) * B)
    constexpr float SCALE = 1.0f / (120.0f * 16383.0f * 16.0f);
    atomicAdd(out, s_red[0] * SCALE);
  }
}

extern "C" void kernel_launch(void* const* d_in, const int* in_sizes, int n_in,
                              void* d_out, int out_size, void* d_ws, size_t ws_size,
                              hipStream_t stream) {
  const float* x   = (const float*)d_in[0];
  const float* w   = (const float*)d_in[1];
  const int*   sel = (const int*)d_in[2];
  float*       out = (float*)d_out;

  int*   perm_tbl = (int*)d_ws;
  float* wgh_tbl  = (float*)((char*)d_ws + CH * sizeof(int));
  float* part     = (float*)((char*)d_ws + 2 * CH * sizeof(int)); // 4096*120 floats

  // d_out is re-poisoned before every launch; zero it for the atomics.
  hipMemsetAsync(d_out, 0, sizeof(float), stream);

  hipLaunchKernelGGL(topk_kernel, dim3(C_), dim3(64), 0, stream,
                     w, sel, perm_tbl, wgh_tbl);
  hipLaunchKernelGGL(gram_part_kernel, dim3(B_ * G_ * NSPLIT), dim3(256), 0, stream,
                     x, perm_tbl, part);
  hipLaunchKernelGGL(finalize_kernel, dim3(B_ * G_), dim3(128), 0, stream,
                     part, wgh_tbl, out);
}